// Round 1
// baseline (26.952 us; speedup 1.0000x reference)
//
#include <hip/hip_runtime.h>
#include <hip/hip_bf16.h>

// x: (N=8, C=512, T=32, H=14, W=14) fp32, contiguous. Row = one (n,c,t): 196 floats.
// Stage 1: GAP over H,W -> gap[(n*C+c)*T + t]  (stored in d_ws)
// Stage 2: out[n,c,t] = sigmoid( sum_k w[k] * gap[n, c+k-2, t] ), zero-pad on c.

#define HW 196          // 14*14
#define HW4 49          // 196/4 float4s per row

__global__ void gap_kernel(const float* __restrict__ x,
                           float* __restrict__ gap,
                           int total_rows) {
    const int waves_per_block = blockDim.x >> 6;
    const int row  = blockIdx.x * waves_per_block + (threadIdx.x >> 6);
    const int lane = threadIdx.x & 63;
    if (row >= total_rows) return;

    const float4* p = reinterpret_cast<const float4*>(x + (size_t)row * HW);
    float s = 0.0f;
    if (lane < HW4) {
        float4 v = p[lane];
        s = (v.x + v.y) + (v.z + v.w);
    }
    // 64-lane butterfly reduce
    #pragma unroll
    for (int off = 32; off > 0; off >>= 1)
        s += __shfl_down(s, off, 64);

    if (lane == 0) gap[row] = s * (1.0f / 196.0f);
}

__global__ void conv_sig_kernel(const float* __restrict__ gap,
                                const float* __restrict__ w,
                                float* __restrict__ out,
                                int N, int C, int T) {
    const int idx = blockIdx.x * blockDim.x + threadIdx.x;
    const int total = N * C * T;
    if (idx >= total) return;

    const int t = idx % T;
    const int c = (idx / T) % C;
    const int n = idx / (T * C);

    const float w0 = w[0], w1 = w[1], w2 = w[2], w3 = w[3], w4 = w[4];

    const float* g = gap + ((size_t)n * C) * T + t;
    float acc = 0.0f;
    if (c >= 2)      acc += w0 * g[(c - 2) * T];
    if (c >= 1)      acc += w1 * g[(c - 1) * T];
                     acc += w2 * g[c * T];
    if (c + 1 < C)   acc += w3 * g[(c + 1) * T];
    if (c + 2 < C)   acc += w4 * g[(c + 2) * T];

    out[idx] = 1.0f / (1.0f + __expf(-acc));
}

extern "C" void kernel_launch(void* const* d_in, const int* in_sizes, int n_in,
                              void* d_out, int out_size, void* d_ws, size_t ws_size,
                              hipStream_t stream) {
    const float* x = (const float*)d_in[0];   // 8*512*32*14*14
    const float* w = (const float*)d_in[1];   // 5
    float* out = (float*)d_out;               // 8*512*32
    float* gap = (float*)d_ws;                // 131072 floats scratch

    const int N = 8, C = 512, T = 32;
    const int total_rows = N * C * T;         // 131072

    // Stage 1: 4 waves per 256-thread block, one wave per row.
    const int waves_per_block = 4;
    const int blocks1 = (total_rows + waves_per_block - 1) / waves_per_block;
    gap_kernel<<<blocks1, waves_per_block * 64, 0, stream>>>(x, gap, total_rows);

    // Stage 2: one thread per output element.
    const int threads2 = 256;
    const int blocks2 = (total_rows + threads2 - 1) / threads2;
    conv_sig_kernel<<<blocks2, threads2, 0, stream>>>(gap, w, out, N, C, T);
}

// Round 2
// 26.100 us; speedup vs baseline: 1.0327x; 1.0327x over previous
//
#include <hip/hip_runtime.h>
#include <hip/hip_bf16.h>

// x: (N=8, C=512, T=32, H=14, W=14) fp32 contiguous.
// Fused: per block = one (n,t). 16 waves x 32 rows: GAP over HW=196 -> LDS[512],
// then 5-tap conv over channel axis + sigmoid -> out[(n*C+c)*T + t].

#define HW 196          // 14*14
#define HW4 49          // float4s per row
#define C_ 512
#define T_ 32

__global__ __launch_bounds__(1024) void fused_attn_kernel(
        const float* __restrict__ x,
        const float* __restrict__ w,
        float* __restrict__ out) {
    const int b    = blockIdx.x;      // 0..N*T-1
    const int t    = b & (T_ - 1);
    const int n    = b >> 5;          // b / 32
    const int wave = threadIdx.x >> 6;  // 0..15
    const int lane = threadIdx.x & 63;

    __shared__ float gap[C_];

    // Base of row (n, c=0, t): x + ((n*C + 0)*T + t)*HW ; row c at +c*T*HW floats
    const float* xb = x + ((size_t)(n * C_) * T_ + t) * HW;

    // Each wave reduces 32 consecutive channels.
    #pragma unroll 4
    for (int i = 0; i < 32; ++i) {
        const int c = (wave << 5) + i;
        const float4* p = reinterpret_cast<const float4*>(xb + (size_t)c * (T_ * HW));
        float s = 0.0f;
        if (lane < HW4) {
            float4 v = p[lane];
            s = (v.x + v.y) + (v.z + v.w);
        }
        #pragma unroll
        for (int off = 32; off > 0; off >>= 1)
            s += __shfl_down(s, off, 64);
        if (lane == 0) gap[c] = s * (1.0f / 196.0f);
    }
    __syncthreads();

    // Conv(k=5, pad=2) over channel axis + sigmoid; threads 0..511 one output each.
    const int c = threadIdx.x;
    if (c < C_) {
        const float w0 = w[0], w1 = w[1], w2 = w[2], w3 = w[3], w4 = w[4];
        float acc = w2 * gap[c];
        if (c >= 2)     acc += w0 * gap[c - 2];
        if (c >= 1)     acc += w1 * gap[c - 1];
        if (c + 1 < C_) acc += w3 * gap[c + 1];
        if (c + 2 < C_) acc += w4 * gap[c + 2];
        out[((size_t)n * C_ + c) * T_ + t] = 1.0f / (1.0f + __expf(-acc));
    }
}

extern "C" void kernel_launch(void* const* d_in, const int* in_sizes, int n_in,
                              void* d_out, int out_size, void* d_ws, size_t ws_size,
                              hipStream_t stream) {
    const float* x = (const float*)d_in[0];   // 8*512*32*14*14
    const float* w = (const float*)d_in[1];   // 5
    float* out = (float*)d_out;               // 8*512*32

    const int N = 8;
    fused_attn_kernel<<<N * T_, 1024, 0, stream>>>(x, w, out);
}

// Round 3
// 24.254 us; speedup vs baseline: 1.1113x; 1.0761x over previous
//
#include <hip/hip_runtime.h>
#include <hip/hip_bf16.h>

// x: (N=8, C=512, T=32, H=14, W=14) fp32 contiguous = 131072 rows x 196 floats.
// Kernel A: contiguous-streaming GAP. Each block = 64 consecutive rows
//   (= 64*49 = 3136 float4s, one contiguous 50176-B slab). Phase 1: 256 threads
//   stream float4s (full lane utilization), write per-float4 partial sums to LDS.
//   Phase 2: segment s (0..63) = exactly 49 partials; one thread each.
// Kernel B: 5-tap conv over channel axis + sigmoid, gap is L2-resident.

#define ROWS_PER_BLOCK 64
#define F4_PER_ROW 49
#define F4_PER_BLOCK (ROWS_PER_BLOCK * F4_PER_ROW)   // 3136
#define THREADS_A 256

__global__ __launch_bounds__(THREADS_A) void gap_kernel(
        const float* __restrict__ x,
        float* __restrict__ gap) {
    __shared__ float part[F4_PER_BLOCK];

    const int tid = threadIdx.x;
    const float4* p = reinterpret_cast<const float4*>(x) +
                      (size_t)blockIdx.x * F4_PER_BLOCK;

    // Phase 1: contiguous stream, one partial per float4.
    #pragma unroll
    for (int j = tid; j < F4_PER_BLOCK; j += THREADS_A) {
        float4 v = p[j];
        part[j] = (v.x + v.y) + (v.z + v.w);
    }
    __syncthreads();

    // Phase 2: 64 segments, 49 partials each (stride 49 = conflict-free).
    if (tid < ROWS_PER_BLOCK) {
        const float* q = &part[tid * F4_PER_ROW];
        float s = 0.0f;
        #pragma unroll
        for (int k = 0; k < F4_PER_ROW; ++k) s += q[k];
        gap[(size_t)blockIdx.x * ROWS_PER_BLOCK + tid] = s * (1.0f / 196.0f);
    }
}

__global__ void conv_sig_kernel(const float* __restrict__ gap,
                                const float* __restrict__ w,
                                float* __restrict__ out,
                                int N, int C, int T) {
    const int idx = blockIdx.x * blockDim.x + threadIdx.x;
    const int total = N * C * T;
    if (idx >= total) return;

    const int t = idx % T;
    const int c = (idx / T) % C;
    const int n = idx / (T * C);

    const float w0 = w[0], w1 = w[1], w2 = w[2], w3 = w[3], w4 = w[4];

    const float* g = gap + ((size_t)n * C) * T + t;
    float acc = w2 * g[c * T];
    if (c >= 2)      acc += w0 * g[(c - 2) * T];
    if (c >= 1)      acc += w1 * g[(c - 1) * T];
    if (c + 1 < C)   acc += w3 * g[(c + 1) * T];
    if (c + 2 < C)   acc += w4 * g[(c + 2) * T];

    out[idx] = 1.0f / (1.0f + __expf(-acc));
}

extern "C" void kernel_launch(void* const* d_in, const int* in_sizes, int n_in,
                              void* d_out, int out_size, void* d_ws, size_t ws_size,
                              hipStream_t stream) {
    const float* x = (const float*)d_in[0];   // 8*512*32*14*14
    const float* w = (const float*)d_in[1];   // 5
    float* out = (float*)d_out;               // 8*512*32
    float* gap = (float*)d_ws;                // 131072 floats scratch

    const int N = 8, C = 512, T = 32;
    const int total_rows = N * C * T;         // 131072
    const int blocksA = total_rows / ROWS_PER_BLOCK;  // 2048

    gap_kernel<<<blocksA, THREADS_A, 0, stream>>>(x, gap);

    const int threadsB = 256;
    const int blocksB = (total_rows + threadsB - 1) / threadsB;
    conv_sig_kernel<<<blocksB, threadsB, 0, stream>>>(gap, w, out, N, C, T);
}

// Round 4
// 23.691 us; speedup vs baseline: 1.1376x; 1.0237x over previous
//
#include <hip/hip_runtime.h>
#include <hip/hip_bf16.h>

// x: (N=8, C=512, T=32, H=14, W=14) fp32 contiguous = 131072 rows x 196 floats.
// Kernel A: contiguous-streaming GAP, registers-first.
//   Block = 64 consecutive rows = 3136 float4s = one contiguous 50 KB slab.
//   Phase 1: 256 threads issue 12-13 independent float4 loads each (static reg
//   slots), then reduce each to a scalar partial in LDS (conflict-free writes).
//   Phase 2: 4 threads per row-segment (12/12/12/13 partials) + 2x shfl_xor.
// Kernel B: 5-tap conv over channel axis + sigmoid; gap (512 KB) is L2-resident.

#define ROWS_PER_BLOCK 64
#define F4_PER_ROW 49
#define F4_PER_BLOCK (ROWS_PER_BLOCK * F4_PER_ROW)   // 3136 = 12*256 + 64
#define THREADS_A 256

__global__ __launch_bounds__(THREADS_A) void gap_kernel(
        const float* __restrict__ x,
        float* __restrict__ gap) {
    __shared__ float part[F4_PER_BLOCK];

    const int tid = threadIdx.x;
    const float4* p = reinterpret_cast<const float4*>(x) +
                      (size_t)blockIdx.x * F4_PER_BLOCK;

    // Phase 1a: issue all loads into static register slots (max MLP).
    float4 v[13];
    #pragma unroll
    for (int i = 0; i < 12; ++i) v[i] = p[tid + i * THREADS_A];
    const bool extra = tid < (F4_PER_BLOCK - 12 * THREADS_A);   // tid < 64
    if (extra) v[12] = p[tid + 12 * THREADS_A];

    // Phase 1b: reduce each float4 to a scalar partial in LDS.
    #pragma unroll
    for (int i = 0; i < 12; ++i)
        part[tid + i * THREADS_A] = (v[i].x + v[i].y) + (v[i].z + v[i].w);
    if (extra)
        part[tid + 12 * THREADS_A] = (v[12].x + v[12].y) + (v[12].z + v[12].w);
    __syncthreads();

    // Phase 2: 4 threads per segment; q=0..2 sum 12, q=3 sums 13.
    const int s = tid >> 2;
    const int q = tid & 3;
    const float* base = &part[s * F4_PER_ROW + q * 12];
    float sum = 0.0f;
    #pragma unroll
    for (int i = 0; i < 12; ++i) sum += base[i];
    if (q == 3) sum += base[12];

    sum += __shfl_xor(sum, 1, 64);
    sum += __shfl_xor(sum, 2, 64);

    if (q == 0)
        gap[(size_t)blockIdx.x * ROWS_PER_BLOCK + s] = sum * (1.0f / 196.0f);
}

__global__ void conv_sig_kernel(const float* __restrict__ gap,
                                const float* __restrict__ w,
                                float* __restrict__ out,
                                int N, int C, int T) {
    const int idx = blockIdx.x * blockDim.x + threadIdx.x;
    const int total = N * C * T;
    if (idx >= total) return;

    const int t = idx % T;
    const int c = (idx / T) % C;
    const int n = idx / (T * C);

    const float w0 = w[0], w1 = w[1], w2 = w[2], w3 = w[3], w4 = w[4];

    const float* g = gap + ((size_t)n * C) * T + t;
    float acc = w2 * g[c * T];
    if (c >= 2)      acc += w0 * g[(c - 2) * T];
    if (c >= 1)      acc += w1 * g[(c - 1) * T];
    if (c + 1 < C)   acc += w3 * g[(c + 1) * T];
    if (c + 2 < C)   acc += w4 * g[(c + 2) * T];

    out[idx] = 1.0f / (1.0f + __expf(-acc));
}

extern "C" void kernel_launch(void* const* d_in, const int* in_sizes, int n_in,
                              void* d_out, int out_size, void* d_ws, size_t ws_size,
                              hipStream_t stream) {
    const float* x = (const float*)d_in[0];   // 8*512*32*14*14
    const float* w = (const float*)d_in[1];   // 5
    float* out = (float*)d_out;               // 8*512*32
    float* gap = (float*)d_ws;                // 131072 floats scratch

    const int N = 8, C = 512, T = 32;
    const int total_rows = N * C * T;         // 131072
    const int blocksA = total_rows / ROWS_PER_BLOCK;  // 2048

    gap_kernel<<<blocksA, THREADS_A, 0, stream>>>(x, gap);

    const int threadsB = 256;
    const int blocksB = (total_rows + threadsB - 1) / threadsB;
    conv_sig_kernel<<<blocksB, threadsB, 0, stream>>>(gap, w, out, N, C, T);
}

// Round 5
// 23.312 us; speedup vs baseline: 1.1562x; 1.0163x over previous
//
#include <hip/hip_runtime.h>
#include <hip/hip_bf16.h>

// x: (N=8, C=512, T=32, H=14, W=14) fp32 contiguous = 131072 rows x 196 floats.
// Kernel A (GAP), LDS-free: block = 64 consecutive rows (contiguous 50 KB slab).
//   4 threads per row: thread q of row s reads float4s {q, q+4, ..., <=48}
//   (256-B stride; a wave covers 16 rows, every 128-B line fully consumed),
//   accumulates in one rolling float4 (~24 VGPR -> 32 waves/CU), then
//   2x shfl_xor quad-combine -> row sum. No LDS, no barrier.
// Kernel B: 5-tap conv over channel axis + sigmoid; gap (512 KB) is L2-resident.

#define ROWS_PER_BLOCK 64
#define F4_PER_ROW 49
#define F4_PER_BLOCK (ROWS_PER_BLOCK * F4_PER_ROW)   // 3136
#define THREADS_A 256

__global__ __launch_bounds__(THREADS_A) void gap_kernel(
        const float* __restrict__ x,
        float* __restrict__ gap) {
    const int tid = threadIdx.x;
    const int s = tid >> 2;     // row within block, 0..63
    const int q = tid & 3;      // quad lane, 0..3

    const float4* p = reinterpret_cast<const float4*>(x) +
                      (size_t)blockIdx.x * F4_PER_BLOCK + s * F4_PER_ROW + q;

    // 12 strided loads for everyone (j = q + 4i, i=0..11 -> j <= 47),
    // plus j=48 for q==0. Two rolling accumulators for ILP.
    float4 a0 = p[0];
    float4 a1 = p[4];
    #pragma unroll
    for (int i = 2; i < 12; i += 2) {
        float4 u = p[4 * i];
        float4 w = p[4 * (i + 1)];
        a0.x += u.x; a0.y += u.y; a0.z += u.z; a0.w += u.w;
        a1.x += w.x; a1.y += w.y; a1.z += w.z; a1.w += w.w;
    }
    float sum = ((a0.x + a1.x) + (a0.y + a1.y)) + ((a0.z + a1.z) + (a0.w + a1.w));
    if (q == 0) {
        float4 u = p[48];
        sum += (u.x + u.y) + (u.z + u.w);
    }

    // quad combine
    sum += __shfl_xor(sum, 1, 64);
    sum += __shfl_xor(sum, 2, 64);

    if (q == 0)
        gap[(size_t)blockIdx.x * ROWS_PER_BLOCK + s] = sum * (1.0f / 196.0f);
}

__global__ void conv_sig_kernel(const float* __restrict__ gap,
                                const float* __restrict__ w,
                                float* __restrict__ out,
                                int N, int C, int T) {
    const int idx = blockIdx.x * blockDim.x + threadIdx.x;
    const int total = N * C * T;
    if (idx >= total) return;

    const int t = idx % T;
    const int c = (idx / T) % C;
    const int n = idx / (T * C);

    const float w0 = w[0], w1 = w[1], w2 = w[2], w3 = w[3], w4 = w[4];

    const float* g = gap + ((size_t)n * C) * T + t;
    float acc = w2 * g[c * T];
    if (c >= 2)      acc += w0 * g[(c - 2) * T];
    if (c >= 1)      acc += w1 * g[(c - 1) * T];
    if (c + 1 < C)   acc += w3 * g[(c + 1) * T];
    if (c + 2 < C)   acc += w4 * g[(c + 2) * T];

    out[idx] = 1.0f / (1.0f + __expf(-acc));
}

extern "C" void kernel_launch(void* const* d_in, const int* in_sizes, int n_in,
                              void* d_out, int out_size, void* d_ws, size_t ws_size,
                              hipStream_t stream) {
    const float* x = (const float*)d_in[0];   // 8*512*32*14*14
    const float* w = (const float*)d_in[1];   // 5
    float* out = (float*)d_out;               // 8*512*32
    float* gap = (float*)d_ws;                // 131072 floats scratch

    const int N = 8, C = 512, T = 32;
    const int total_rows = N * C * T;         // 131072
    const int blocksA = total_rows / ROWS_PER_BLOCK;  // 2048

    gap_kernel<<<blocksA, THREADS_A, 0, stream>>>(x, gap);

    const int threadsB = 256;
    const int blocksB = (total_rows + threadsB - 1) / threadsB;
    conv_sig_kernel<<<blocksB, threadsB, 0, stream>>>(gap, w, out, N, C, T);
}